// Round 1
// baseline (11.543 us; speedup 1.0000x reference)
//
#include <hip/hip_runtime.h>
#include <hip/hip_bf16.h>

// Reference analysis:
//   reference() returns broadcast(x[:, -1, :]) to (BATCH, FUTURE, N_IN).
//   The GRU encoder/decoder scans and the linear head are dead code (their
//   results are never part of the returned value). So the kernel is a pure
//   broadcast-copy of the last input timestep.
//
// Shapes: x: (256, 128, 512) f32  ->  out: (256, 32, 512) f32
//   out[b, f, i] = x[b, 127, i]
//
// Vectorized as float4: out has 256*32*128 = 1,048,576 float4 elements.

#define BATCH 256
#define INPUT_LEN 128
#define N_IN 512
#define FUTURE 32

__global__ __launch_bounds__(256) void bcast_last_step_kernel(
    const float4* __restrict__ x, float4* __restrict__ out) {
    const int idx = blockIdx.x * blockDim.x + threadIdx.x;  // [0, 1048576)
    const int i4 = idx & (N_IN / 4 - 1);   // float4 index within row: [0,128)
    const int bf = idx >> 7;               // b*FUTURE + f
    const int b  = bf >> 5;                // [0,256)
    // input float4 offset: b*(INPUT_LEN*N_IN/4) + (INPUT_LEN-1)*(N_IN/4) + i4
    out[idx] = x[b * (INPUT_LEN * N_IN / 4) + (INPUT_LEN - 1) * (N_IN / 4) + i4];
}

extern "C" void kernel_launch(void* const* d_in, const int* in_sizes, int n_in,
                              void* d_out, int out_size, void* d_ws, size_t ws_size,
                              hipStream_t stream) {
    const float4* x = (const float4*)d_in[0];
    float4* out = (float4*)d_out;
    // out_size = 256*32*512 = 4,194,304 floats = 1,048,576 float4
    const int n4 = BATCH * FUTURE * (N_IN / 4);
    const int block = 256;
    const int grid = n4 / block;  // 4096
    bcast_last_step_kernel<<<grid, block, 0, stream>>>(x, out);
}

// Round 2
// 11.233 us; speedup vs baseline: 1.0276x; 1.0276x over previous
//
#include <hip/hip_runtime.h>
#include <hip/hip_bf16.h>

// reference() returns broadcast(x[:, -1, :]) to (BATCH, FUTURE, N_IN); the
// GRU scans and linear head are dead code. Pure broadcast-copy:
//   out[b, f, i] = x[b, 127, i]
// x: (256, 128, 512) f32, out: (256, 32, 512) f32.
//
// v2: register reuse of the 32x broadcast — each thread loads its input
// float4 once and stores 4 FUTURE rows. 262,144 threads, 1024 blocks.

#define BATCH 256
#define INPUT_LEN 128
#define N_IN 512
#define FUTURE 32
#define ROW4 (N_IN / 4)          // 128 float4 per row
#define F_PER_THREAD 4

__global__ __launch_bounds__(256) void bcast_last_step_kernel(
    const float4* __restrict__ x, float4* __restrict__ out) {
    const int idx = blockIdx.x * blockDim.x + threadIdx.x;  // [0, 262144)
    const int i4 = idx & (ROW4 - 1);       // [0,128)
    const int t  = idx >> 7;               // [0,2048) = b*8 + fq
    const int b  = t >> 3;                 // [0,256)
    const int fq = t & 7;                  // [0,8) -> f = fq*4 .. fq*4+3

    const float4 v = x[b * (INPUT_LEN * ROW4) + (INPUT_LEN - 1) * ROW4 + i4];

    float4* o = out + (b * FUTURE + fq * F_PER_THREAD) * ROW4 + i4;
#pragma unroll
    for (int f = 0; f < F_PER_THREAD; ++f) {
        o[f * ROW4] = v;
    }
}

extern "C" void kernel_launch(void* const* d_in, const int* in_sizes, int n_in,
                              void* d_out, int out_size, void* d_ws, size_t ws_size,
                              hipStream_t stream) {
    const float4* x = (const float4*)d_in[0];
    float4* out = (float4*)d_out;
    const int nthreads = BATCH * (FUTURE / F_PER_THREAD) * ROW4;  // 262,144
    const int block = 256;
    const int grid = nthreads / block;  // 1024
    bcast_last_step_kernel<<<grid, block, 0, stream>>>(x, out);
}